// Round 1
// baseline (457.221 us; speedup 1.0000x reference)
//
#include <hip/hip_runtime.h>

typedef __bf16 bf16;
typedef __attribute__((ext_vector_type(8))) __bf16 bf16x8;
typedef __attribute__((ext_vector_type(4))) __bf16 bf16x4;
typedef __attribute__((ext_vector_type(4))) float f32x4;

#define MFMA16(a, b, c) __builtin_amdgcn_mfma_f32_16x16x32_bf16(a, b, c, 0, 0, 0)

__device__ __forceinline__ int div7(int n) { return (n * 37) >> 8; }          // exact 0..63
__device__ __forceinline__ int relv(int n) { return n + 6 * div7(n); }        // 13*(n/7)+(n%7)

// Load 8 consecutive fp32, round to bf16x8 (RNE via cast).
__device__ __forceinline__ bf16x8 LD8(const float* p) {
    f32x4 a = *(const f32x4*)p;
    f32x4 b = *(const f32x4*)(p + 4);
    bf16x8 r;
    r[0] = (bf16)a[0]; r[1] = (bf16)a[1]; r[2] = (bf16)a[2]; r[3] = (bf16)a[3];
    r[4] = (bf16)b[0]; r[5] = (bf16)b[1]; r[6] = (bf16)b[2]; r[7] = (bf16)b[3];
    return r;
}

// One block = one 7x7 window. 256 threads = 4 waves. ONE barrier total.
// Key layout trick: S^T = MFMA(K,Q) puts keys in regs / queries in lanes.
// K is stored at permuted LDS row rho(key) (field swizzle) so that the
// softmax result e[i] IS the PV B-fragment (bp0=e[0..7], bp1=e[8..15]),
// and proj is computed operand-swapped with column-permuted proj_w reads,
// so P and O stay entirely in registers.
__global__ __launch_bounds__(256, 4)
void swin_msa_kernel(const float* __restrict__ x_in,   const float* __restrict__ sx_in,
                     const float* __restrict__ qkv_w,  const float* __restrict__ qkv_b,
                     const float* __restrict__ skip_w, const float* __restrict__ skip_b,
                     const float* __restrict__ proj_w, const float* __restrict__ proj_b,
                     const float* __restrict__ btab,   float* __restrict__ out)
{
    // LDS: Kb 64x104 (rows permuted by rho), Qb 64x104, VT 96x72 = 40448 B -> 4 blocks/CU
    __shared__ __align__(16) unsigned short smem[20224];
    bf16* Kb = (bf16*)smem;       // 64 x 104
    bf16* Qb = Kb + 6656;         // 64 x 104
    bf16* VT = Qb + 6656;         // 96 x 72  (V transposed: [channel][pixel], natural pixel order)

    const int tid  = threadIdx.x;
    const int wv   = tid >> 6;
    const int lane = tid & 63;
    const int quad = lane >> 4;
    const int l16  = lane & 15;

    const int win  = blockIdx.x;
    const int bimg = win >> 10;
    const int wrem = win & 1023;
    const int wi   = wrem >> 5;
    const int wj   = wrem & 31;

    const f32x4 zero4 = {0.f, 0.f, 0.f, 0.f};
    const int koff = quad * 8;          // hardware k-slice base within a 32-wide MFMA step

    // my pixel (A-row for GEMMs, query for attention, store row): p = 16*wv + l16
    const int pq  = 16 * wv + l16;
    const int pqc = (pq < 49) ? pq : 48;                    // clamp pad rows to a real pixel
    int pr = div7(pqc), pc = pqc - 7 * pr;
    int h0 = wi * 7 + pr + 3; if (h0 >= 224) h0 -= 224;     // roll(-3) gather
    int w0 = wj * 7 + pc + 3; if (w0 >= 224) w0 -= 224;
    const int gbase = ((bimg * 224 + h0) * 224 + w0) * 96;

    // ---- stage B1: KV = X @ qkv_w^T + b (M-split: wave owns its 16 pixel rows) ----
    {
        f32x4 acc[12];
        #pragma unroll
        for (int t = 0; t < 12; ++t) acc[t] = zero4;
        #pragma unroll
        for (int ks = 0; ks < 3; ++ks) {
            bf16x8 a = LD8(x_in + gbase + ks * 32 + koff);
            #pragma unroll
            for (int t = 0; t < 12; ++t) {
                bf16x8 b = LD8(qkv_w + (16 * t + l16) * 96 + ks * 32 + koff);
                acc[t] = MFMA16(a, b, acc[t]);
            }
        }
        // K rows written at rho(key): key=16wv+4quad+r -> row 32(wv>>1)+16(quad&1)+8(wv&1)+4(quad>>1)+r
        const int rho = 32 * (wv >> 1) + 16 * (quad & 1) + 8 * (wv & 1) + 4 * (quad >> 1);
        #pragma unroll
        for (int t = 0; t < 6; ++t) {
            const float bias = qkv_b[16 * t + l16];
            #pragma unroll
            for (int r = 0; r < 4; ++r)
                Kb[(rho + r) * 104 + 16 * t + l16] = (bf16)(acc[t][r] + bias);
        }
        const int pout = 16 * wv + 4 * quad;     // natural pixel index of my acc rows
        #pragma unroll
        for (int t = 6; t < 12; ++t) {
            const float bias = qkv_b[16 * t + l16];
            const int ch = 16 * (t - 6) + l16;
            bf16x4 vv;
            #pragma unroll
            for (int r = 0; r < 4; ++r) vv[r] = (bf16)(acc[t][r] + bias);
            *(bf16x4*)(VT + ch * 72 + pout) = vv;
        }
    }
    // ---- stage B2: Q = SX @ skip_w^T + b ----
    {
        f32x4 qa[6];
        #pragma unroll
        for (int t = 0; t < 6; ++t) qa[t] = zero4;
        #pragma unroll
        for (int ks = 0; ks < 3; ++ks) {
            bf16x8 a = LD8(sx_in + gbase + ks * 32 + koff);
            #pragma unroll
            for (int t = 0; t < 6; ++t) {
                bf16x8 b = LD8(skip_w + (16 * t + l16) * 96 + ks * 32 + koff);
                qa[t] = MFMA16(a, b, qa[t]);
            }
        }
        const int row = 16 * wv + 4 * quad;
        #pragma unroll
        for (int t = 0; t < 6; ++t) {
            const float bias = skip_b[16 * t + l16];
            #pragma unroll
            for (int r = 0; r < 4; ++r)
                Qb[(row + r) * 104 + 16 * t + l16] = (bf16)(qa[t][r] + bias);
        }
    }
    __syncthreads();   // the only barrier: Kb/Qb/VT now visible, read-only hereafter

    // ---- stage C: attention + proj, fully in registers ----
    // slot (nt,r) at this lane holds key = 8*quad + 32*(nt>>1) + 4*(nt&1) + r
    int bofs[16];
    unsigned ibits = 0, mbits = 0;
    const int rvq = relv(pqc);
    const float* btq = btab + rvq * 3;
    {
        const bool bnd = (wi == 31) || (wj == 31);
        int gq = 0;
        if (bnd) {
            int rqq = div7(pqc), cqq = pqc - 7 * rqq;
            gq = (wi == 31 ? (rqq < 4 ? 3 : 6) : 0) + (wj == 31 ? (cqq < 4 ? 1 : 2) : 0);
        }
        #pragma unroll
        for (int nt = 0; nt < 4; ++nt) {
            #pragma unroll
            for (int r = 0; r < 4; ++r) {
                const int i = nt * 4 + r;
                int key = 8 * quad + 32 * (nt >> 1) + 4 * (nt & 1) + r;
                if (key >= 49) ibits |= (1u << i);
                int kk = 48 - key; kk = (kk < 0) ? 0 : kk;
                bofs[i] = relv(kk) * 3;                       // flipped key rel-index * 3
                if (bnd) {
                    int rk = div7(key), ck = key - 7 * rk;
                    int gk = (wi == 31 ? (rk < 4 ? 3 : 6) : 0) + (wj == 31 ? (ck < 4 ? 1 : 2) : 0);
                    if (gk != gq) mbits |= (1u << i);
                }
            }
        }
    }

    const float scale = 0.17677669529663687f;   // 32^-0.5
    f32x4 dacc[6];
    #pragma unroll
    for (int t = 0; t < 6; ++t) dacc[t] = zero4;

    #pragma unroll
    for (int h = 0; h < 3; ++h) {
        // S^T = K_perm . Q^T : rows = permuted keys, cols = queries (l16)
        const bf16x8 bq = *(const bf16x8*)(Qb + (16 * wv + l16) * 104 + 32 * h + koff);
        f32x4 s[4];
        #pragma unroll
        for (int nt = 0; nt < 4; ++nt) {
            bf16x8 ak = *(const bf16x8*)(Kb + (16 * nt + l16) * 104 + 32 * h + koff);
            s[nt] = MFMA16(ak, bq, zero4);
        }
        float v[16];
        #pragma unroll
        for (int nt = 0; nt < 4; ++nt)
            #pragma unroll
            for (int r = 0; r < 4; ++r) {
                const int i = nt * 4 + r;
                float x = s[nt][r] * scale + btq[bofs[i] + h];
                x = ((mbits >> i) & 1) ? x - 100.f : x;
                v[i] = ((ibits >> i) & 1) ? -20000.f : x;
            }
        // softmax over 64 keys: 16 in-lane + 2 cross-quad shuffles
        float m01 = fmaxf(fmaxf(v[0], v[1]), fmaxf(v[2], v[3]));
        float m23 = fmaxf(fmaxf(v[4], v[5]), fmaxf(v[6], v[7]));
        float m45 = fmaxf(fmaxf(v[8], v[9]), fmaxf(v[10], v[11]));
        float m67 = fmaxf(fmaxf(v[12], v[13]), fmaxf(v[14], v[15]));
        float mx = fmaxf(fmaxf(m01, m23), fmaxf(m45, m67));
        mx = fmaxf(mx, __shfl_xor(mx, 16));
        mx = fmaxf(mx, __shfl_xor(mx, 32));
        #pragma unroll
        for (int i = 0; i < 16; ++i) v[i] = __expf(v[i] - mx);
        float s01 = (v[0] + v[1]) + (v[2] + v[3]);
        float s23 = (v[4] + v[5]) + (v[6] + v[7]);
        float s45 = (v[8] + v[9]) + (v[10] + v[11]);
        float s67 = (v[12] + v[13]) + (v[14] + v[15]);
        float sm = (s01 + s23) + (s45 + s67);
        sm += __shfl_xor(sm, 16);
        sm += __shfl_xor(sm, 32);
        const float isv = 1.0f / sm;

        // PV (operand-swapped): O^T = V^T . P^T ; thanks to rho, B-frag is just e[0..7]/e[8..15]
        bf16x8 bp0, bp1;
        #pragma unroll
        for (int j = 0; j < 8; ++j) { bp0[j] = (bf16)v[j]; bp1[j] = (bf16)v[8 + j]; }
        const bf16* vb = VT + (32 * h + l16) * 72 + koff;
        f32x4 o0 = zero4, o1 = zero4;
        o0 = MFMA16(*(const bf16x8*)(vb),            bp0, o0);
        o0 = MFMA16(*(const bf16x8*)(vb + 32),       bp1, o0);
        o1 = MFMA16(*(const bf16x8*)(vb + 16 * 72),      bp0, o1);
        o1 = MFMA16(*(const bf16x8*)(vb + 16 * 72 + 32), bp1, o1);

        // proj (operand-swapped, fused per head): out^T += W(:, head h cols, permuted) . O_h^T
        bf16x8 bo;
        #pragma unroll
        for (int r = 0; r < 4; ++r) { bo[r] = (bf16)(o0[r] * isv); bo[4 + r] = (bf16)(o1[r] * isv); }
        #pragma unroll
        for (int t = 0; t < 6; ++t) {
            const float* pw = proj_w + (16 * t + l16) * 96 + 32 * h + 4 * quad;
            f32x4 w0c = *(const f32x4*)pw;          // channels 32h + 4q .. +3
            f32x4 w1c = *(const f32x4*)(pw + 16);   // channels 32h + 16 + 4q .. +3
            bf16x8 aw;
            #pragma unroll
            for (int r = 0; r < 4; ++r) { aw[r] = (bf16)w0c[r]; aw[4 + r] = (bf16)w1c[r]; }
            dacc[t] = MFMA16(aw, bo, dacc[t]);
        }
    }

    // ---- store: out^T rows = outc (16t+4q+r consecutive -> dwordx4), col = my pixel ----
    if (pq < 49) {
        #pragma unroll
        for (int t = 0; t < 6; ++t) {
            const f32x4 pb = *(const f32x4*)(proj_b + 16 * t + 4 * quad);
            f32x4 ov;
            #pragma unroll
            for (int r = 0; r < 4; ++r) ov[r] = dacc[t][r] + pb[r];
            *(f32x4*)(out + gbase + 16 * t + 4 * quad) = ov;
        }
    }
}

extern "C" void kernel_launch(void* const* d_in, const int* in_sizes, int n_in,
                              void* d_out, int out_size, void* d_ws, size_t ws_size,
                              hipStream_t stream) {
    (void)in_sizes; (void)n_in; (void)out_size; (void)d_ws; (void)ws_size;
    swin_msa_kernel<<<dim3(4096), dim3(256), 0, stream>>>(
        (const float*)d_in[0], (const float*)d_in[1], (const float*)d_in[2],
        (const float*)d_in[3], (const float*)d_in[4], (const float*)d_in[5],
        (const float*)d_in[6], (const float*)d_in[7], (const float*)d_in[8],
        (float*)d_out);
}

// Round 2
// 309.179 us; speedup vs baseline: 1.4788x; 1.4788x over previous
//
#include <hip/hip_runtime.h>

typedef __bf16 bf16;
typedef __attribute__((ext_vector_type(8))) __bf16 bf16x8;
typedef __attribute__((ext_vector_type(4))) __bf16 bf16x4;
typedef __attribute__((ext_vector_type(4))) float f32x4;

#define MFMA16(a, b, c) __builtin_amdgcn_mfma_f32_16x16x32_bf16(a, b, c, 0, 0, 0)

__device__ __forceinline__ int div7(int n) { return (n * 37) >> 8; }          // exact 0..63
__device__ __forceinline__ int relv(int n) { return n + 6 * div7(n); }        // 13*(n/7)+(n%7)

// Streaming load of 8 consecutive fp32 (nontemporal: read-once data), round to bf16x8.
__device__ __forceinline__ bf16x8 LD8NT(const float* p) {
    f32x4 a = __builtin_nontemporal_load((const f32x4*)p);
    f32x4 b = __builtin_nontemporal_load((const f32x4*)(p + 4));
    bf16x8 r;
    r[0] = (bf16)a[0]; r[1] = (bf16)a[1]; r[2] = (bf16)a[2]; r[3] = (bf16)a[3];
    r[4] = (bf16)b[0]; r[5] = (bf16)b[1]; r[6] = (bf16)b[2]; r[7] = (bf16)b[3];
    return r;
}

// ---------------- prep: pack weights into MFMA B-fragment order (bf16) ----------------
// ws layout, in bf16x8 (16 B) fragments:
//   [0   , 2304): Wq  [t=0..11][ks=0..2][lane] = qkv_w [(16t+l16)*96 + ks*32 + q*8 + e], e=0..7
//   [2304, 3456): Wsk [t=0..5 ][ks=0..2][lane] = skip_w[(16t+l16)*96 + ks*32 + q*8 + e]
//   [3456, 4608): Wpr [t=0..5 ][h =0..2][lane] = proj_w[(16t+l16)*96 + 32h + 4q + r] (r=0..3),
//                                                then the same +16 in elems 4..7
__global__ __launch_bounds__(256)
void pack_weights(const float* __restrict__ qkv_w, const float* __restrict__ skip_w,
                  const float* __restrict__ proj_w, bf16* __restrict__ ws)
{
    const int j = blockIdx.x * 256 + threadIdx.x;
    bf16x8 v;
    if (j < 2304) {
        int t = j / 192, rem = j - t * 192;
        int ks = rem >> 6, lane = rem & 63, q = lane >> 4, l16 = lane & 15;
        const float* p = qkv_w + (16 * t + l16) * 96 + ks * 32 + q * 8;
        #pragma unroll
        for (int e = 0; e < 8; ++e) v[e] = (bf16)p[e];
        ((bf16x8*)ws)[j] = v;
    } else if (j < 3456) {
        int i = j - 2304;
        int t = i / 192, rem = i - t * 192;
        int ks = rem >> 6, lane = rem & 63, q = lane >> 4, l16 = lane & 15;
        const float* p = skip_w + (16 * t + l16) * 96 + ks * 32 + q * 8;
        #pragma unroll
        for (int e = 0; e < 8; ++e) v[e] = (bf16)p[e];
        ((bf16x8*)ws)[j] = v;
    } else if (j < 4608) {
        int i = j - 3456;
        int t = i / 192, rem = i - t * 192;
        int h = rem >> 6, lane = rem & 63, q = lane >> 4, l16 = lane & 15;
        const float* p = proj_w + (16 * t + l16) * 96 + 32 * h + 4 * q;
        #pragma unroll
        for (int r = 0; r < 4; ++r) { v[r] = (bf16)p[r]; v[4 + r] = (bf16)p[16 + r]; }
        ((bf16x8*)ws)[j] = v;
    }
}

// ---------------- main: one block = one 7x7 window, 256 threads = 4 waves ----------------
__global__ __launch_bounds__(256, 4)
void swin_msa_kernel(const float* __restrict__ x_in,   const float* __restrict__ sx_in,
                     const bf16*  __restrict__ wpk,    const float* __restrict__ qkv_b,
                     const float* __restrict__ skip_b,
                     const float* __restrict__ proj_b,
                     const float* __restrict__ btab,   float* __restrict__ out)
{
    // LDS: Kb 64x104 (rows permuted by rho), Qb 64x104, VT 96x72 = 40448 B -> 4 blocks/CU
    __shared__ __align__(16) unsigned short smem[20224];
    bf16* Kb = (bf16*)smem;       // 64 x 104
    bf16* Qb = Kb + 6656;         // 64 x 104
    bf16* VT = Qb + 6656;         // 96 x 72  (V transposed: [channel][pixel])

    const int tid  = threadIdx.x;
    const int wv   = tid >> 6;
    const int lane = tid & 63;
    const int quad = lane >> 4;
    const int l16  = lane & 15;

    const int win  = blockIdx.x;
    const int bimg = win >> 10;
    const int wrem = win & 1023;
    const int wi   = wrem >> 5;
    const int wj   = wrem & 31;

    const f32x4 zero4 = {0.f, 0.f, 0.f, 0.f};
    const int koff = quad * 8;

    // packed weight fragment streams for THIS lane (wave reads dense 1 KB per instr)
    const bf16x8* WQ = (const bf16x8*)wpk + lane;          // + (t*3+ks)*64
    const bf16x8* WS = (const bf16x8*)wpk + 2304 + lane;   // + (t*3+ks)*64
    const bf16x8* WP = (const bf16x8*)wpk + 3456 + lane;   // + (t*3+h)*64

    // my pixel: p = 16*wv + l16
    const int pq  = 16 * wv + l16;
    const int pqc = (pq < 49) ? pq : 48;
    int pr = div7(pqc), pc = pqc - 7 * pr;
    int h0 = wi * 7 + pr + 3; if (h0 >= 224) h0 -= 224;     // roll(-3) gather
    int w0 = wj * 7 + pc + 3; if (w0 >= 224) w0 -= 224;
    const int gbase = ((bimg * 224 + h0) * 224 + w0) * 96;

    // ---- stage B1: KV = X @ qkv_w^T + b (M-split: wave owns its 16 pixel rows) ----
    {
        f32x4 acc[12];
        #pragma unroll
        for (int t = 0; t < 12; ++t) acc[t] = zero4;
        #pragma unroll
        for (int ks = 0; ks < 3; ++ks) {
            bf16x8 a = LD8NT(x_in + gbase + ks * 32 + koff);
            #pragma unroll
            for (int t = 0; t < 12; ++t)
                acc[t] = MFMA16(a, WQ[(t * 3 + ks) * 64], acc[t]);
        }
        // K rows at rho(key): key=16wv+4quad+r -> row 32(wv>>1)+16(quad&1)+8(wv&1)+4(quad>>1)+r
        const int rho = 32 * (wv >> 1) + 16 * (quad & 1) + 8 * (wv & 1) + 4 * (quad >> 1);
        #pragma unroll
        for (int t = 0; t < 6; ++t) {
            const float bias = qkv_b[16 * t + l16];
            #pragma unroll
            for (int r = 0; r < 4; ++r)
                Kb[(rho + r) * 104 + 16 * t + l16] = (bf16)(acc[t][r] + bias);
        }
        const int pout = 16 * wv + 4 * quad;
        #pragma unroll
        for (int t = 6; t < 12; ++t) {
            const float bias = qkv_b[16 * t + l16];
            const int ch = 16 * (t - 6) + l16;
            bf16x4 vv;
            #pragma unroll
            for (int r = 0; r < 4; ++r) vv[r] = (bf16)(acc[t][r] + bias);
            *(bf16x4*)(VT + ch * 72 + pout) = vv;
        }
    }
    // ---- stage B2: Q = SX @ skip_w^T + b ----
    {
        f32x4 qa[6];
        #pragma unroll
        for (int t = 0; t < 6; ++t) qa[t] = zero4;
        #pragma unroll
        for (int ks = 0; ks < 3; ++ks) {
            bf16x8 a = LD8NT(sx_in + gbase + ks * 32 + koff);
            #pragma unroll
            for (int t = 0; t < 6; ++t)
                qa[t] = MFMA16(a, WS[(t * 3 + ks) * 64], qa[t]);
        }
        const int row = 16 * wv + 4 * quad;
        #pragma unroll
        for (int t = 0; t < 6; ++t) {
            const float bias = skip_b[16 * t + l16];
            #pragma unroll
            for (int r = 0; r < 4; ++r)
                Qb[(row + r) * 104 + 16 * t + l16] = (bf16)(qa[t][r] + bias);
        }
    }
    __syncthreads();   // the only barrier: Kb/Qb/VT visible, read-only hereafter

    // ---- stage C: attention + proj, fully in registers ----
    // slot (nt,r) at this lane holds key = 8*quad + 32*(nt>>1) + 4*(nt&1) + r
    int bofs[16];
    unsigned ibits = 0, mbits = 0;
    const float* btq = btab + relv(pqc) * 3;
    {
        const bool bnd = (wi == 31) || (wj == 31);
        int gq = 0;
        if (bnd) {
            int rqq = div7(pqc), cqq = pqc - 7 * rqq;
            gq = (wi == 31 ? (rqq < 4 ? 3 : 6) : 0) + (wj == 31 ? (cqq < 4 ? 1 : 2) : 0);
        }
        #pragma unroll
        for (int nt = 0; nt < 4; ++nt) {
            #pragma unroll
            for (int r = 0; r < 4; ++r) {
                const int i = nt * 4 + r;
                int key = 8 * quad + 32 * (nt >> 1) + 4 * (nt & 1) + r;
                if (key >= 49) ibits |= (1u << i);
                int kk = 48 - key; kk = (kk < 0) ? 0 : kk;
                bofs[i] = relv(kk) * 3;                       // flipped key rel-index * 3
                if (bnd) {
                    int rk = div7(key), ck = key - 7 * rk;
                    int gk = (wi == 31 ? (rk < 4 ? 3 : 6) : 0) + (wj == 31 ? (ck < 4 ? 1 : 2) : 0);
                    if (gk != gq) mbits |= (1u << i);
                }
            }
        }
    }

    const float scale = 0.17677669529663687f;   // 32^-0.5
    f32x4 dacc[6];
    #pragma unroll
    for (int t = 0; t < 6; ++t) dacc[t] = zero4;

    #pragma unroll
    for (int h = 0; h < 3; ++h) {
        // S^T = K_perm . Q^T : rows = permuted keys, cols = queries (l16)
        const bf16x8 bq = *(const bf16x8*)(Qb + (16 * wv + l16) * 104 + 32 * h + koff);
        f32x4 s[4];
        #pragma unroll
        for (int nt = 0; nt < 4; ++nt) {
            bf16x8 ak = *(const bf16x8*)(Kb + (16 * nt + l16) * 104 + 32 * h + koff);
            s[nt] = MFMA16(ak, bq, zero4);
        }
        float v[16];
        #pragma unroll
        for (int nt = 0; nt < 4; ++nt)
            #pragma unroll
            for (int r = 0; r < 4; ++r) {
                const int i = nt * 4 + r;
                float x = s[nt][r] * scale + btq[bofs[i] + h];
                x = ((mbits >> i) & 1) ? x - 100.f : x;
                v[i] = ((ibits >> i) & 1) ? -20000.f : x;
            }
        // softmax over 64 keys: 16 in-lane + 2 cross-quad shuffles
        float m01 = fmaxf(fmaxf(v[0], v[1]), fmaxf(v[2], v[3]));
        float m23 = fmaxf(fmaxf(v[4], v[5]), fmaxf(v[6], v[7]));
        float m45 = fmaxf(fmaxf(v[8], v[9]), fmaxf(v[10], v[11]));
        float m67 = fmaxf(fmaxf(v[12], v[13]), fmaxf(v[14], v[15]));
        float mx = fmaxf(fmaxf(m01, m23), fmaxf(m45, m67));
        mx = fmaxf(mx, __shfl_xor(mx, 16));
        mx = fmaxf(mx, __shfl_xor(mx, 32));
        #pragma unroll
        for (int i = 0; i < 16; ++i) v[i] = __expf(v[i] - mx);
        float s01 = (v[0] + v[1]) + (v[2] + v[3]);
        float s23 = (v[4] + v[5]) + (v[6] + v[7]);
        float s45 = (v[8] + v[9]) + (v[10] + v[11]);
        float s67 = (v[12] + v[13]) + (v[14] + v[15]);
        float sm = (s01 + s23) + (s45 + s67);
        sm += __shfl_xor(sm, 16);
        sm += __shfl_xor(sm, 32);
        const float isv = 1.0f / sm;

        // PV (operand-swapped): O^T = V^T . P^T ; rho makes B-frag = e[0..7]/e[8..15]
        bf16x8 bp0, bp1;
        #pragma unroll
        for (int j = 0; j < 8; ++j) { bp0[j] = (bf16)v[j]; bp1[j] = (bf16)v[8 + j]; }
        const bf16* vb = VT + (32 * h + l16) * 72 + koff;
        f32x4 o0 = zero4, o1 = zero4;
        o0 = MFMA16(*(const bf16x8*)(vb),                bp0, o0);
        o0 = MFMA16(*(const bf16x8*)(vb + 32),           bp1, o0);
        o1 = MFMA16(*(const bf16x8*)(vb + 16 * 72),      bp0, o1);
        o1 = MFMA16(*(const bf16x8*)(vb + 16 * 72 + 32), bp1, o1);

        // proj (operand-swapped, fused per head): out^T += Wp(:, head h, permuted) . O_h^T
        bf16x8 bo;
        #pragma unroll
        for (int r = 0; r < 4; ++r) { bo[r] = (bf16)(o0[r] * isv); bo[4 + r] = (bf16)(o1[r] * isv); }
        #pragma unroll
        for (int t = 0; t < 6; ++t)
            dacc[t] = MFMA16(WP[(t * 3 + h) * 64], bo, dacc[t]);
    }

    // ---- store: out^T rows = channels (16t+4q+r consecutive -> dwordx4), col = my pixel ----
    if (pq < 49) {
        #pragma unroll
        for (int t = 0; t < 6; ++t) {
            const f32x4 pb = *(const f32x4*)(proj_b + 16 * t + 4 * quad);
            f32x4 ov;
            #pragma unroll
            for (int r = 0; r < 4; ++r) ov[r] = dacc[t][r] + pb[r];
            *(f32x4*)(out + gbase + 16 * t + 4 * quad) = ov;
        }
    }
}

extern "C" void kernel_launch(void* const* d_in, const int* in_sizes, int n_in,
                              void* d_out, int out_size, void* d_ws, size_t ws_size,
                              hipStream_t stream) {
    (void)in_sizes; (void)n_in; (void)out_size; (void)ws_size;
    pack_weights<<<dim3(18), dim3(256), 0, stream>>>(
        (const float*)d_in[2], (const float*)d_in[4], (const float*)d_in[6], (bf16*)d_ws);
    swin_msa_kernel<<<dim3(4096), dim3(256), 0, stream>>>(
        (const float*)d_in[0], (const float*)d_in[1], (const bf16*)d_ws,
        (const float*)d_in[3], (const float*)d_in[5], (const float*)d_in[7],
        (const float*)d_in[8], (float*)d_out);
}